// Round 1
// baseline (324.556 us; speedup 1.0000x reference)
//
#include <hip/hip_runtime.h>
#include <stdint.h>

typedef int v4i __attribute__((ext_vector_type(4)));

// direct global->LDS DMA, 16B per lane. LDS dest = wave-uniform base + lane*16.
__device__ __forceinline__ void gll16(const void* g, void* l) {
    __builtin_amdgcn_global_load_lds(
        (const __attribute__((address_space(1))) void*)(uintptr_t)g,
        (__attribute__((address_space(3))) void*)(uint32_t)(uintptr_t)l,
        16, 0, 0);
}

// ---------------- Kernel 1: per-row dynamic int8 quantization of x ----------------
// one block (256 threads) per row of 1024 floats; rows >= M are zero pad rows.
__global__ __launch_bounds__(256) void quant_x(const float* __restrict__ x,
                                               signed char* __restrict__ xq,
                                               float* __restrict__ sx, int M) {
    const int row = blockIdx.x;
    const int tid = threadIdx.x;
    signed char* qrow = xq + (size_t)row * 1024;
    if (row >= M) {  // zero the pad rows (uniform branch per block)
        ((char4*)qrow)[tid] = make_char4(0, 0, 0, 0);
        if (tid == 0) sx[row] = 0.0f;
        return;
    }
    const float4 v = ((const float4*)(x + (size_t)row * 1024))[tid];
    float a = fmaxf(fmaxf(fabsf(v.x), fabsf(v.y)), fmaxf(fabsf(v.z), fabsf(v.w)));
#pragma unroll
    for (int off = 32; off > 0; off >>= 1)
        a = fmaxf(a, __shfl_xor(a, off));
    __shared__ float red[4];
    if ((tid & 63) == 0) red[tid >> 6] = a;
    __syncthreads();
    const float am = fmaxf(fmaxf(red[0], red[1]), fmaxf(red[2], red[3]));
    const float amc = fmaxf(am, 1e-8f);
    const float scale = amc * (1.0f / 127.0f);
    const float inv = 127.0f / amc;
    char4 q;
    q.x = (signed char)(int)rintf(v.x * inv);
    q.y = (signed char)(int)rintf(v.y * inv);
    q.z = (signed char)(int)rintf(v.z * inv);
    q.w = (signed char)(int)rintf(v.w * inv);
    ((char4*)qrow)[tid] = q;
    if (tid == 0) sx[row] = scale;
}

// ---------------- Kernel 2: w_int (int32, values in [-127,127]) -> int8 ----------------
__global__ __launch_bounds__(256) void conv_w(const int* __restrict__ w,
                                              signed char* __restrict__ w8, int n4) {
    const int i = blockIdx.x * 256 + threadIdx.x;
    if (i < n4) {
        const int4 v = ((const int4*)w)[i];
        char4 c;
        c.x = (signed char)v.x; c.y = (signed char)v.y;
        c.z = (signed char)v.z; c.w = (signed char)v.w;
        ((char4*)w8)[i] = c;
    }
}

// ---------------- Kernel 3: int8 GEMM (128x128 tile, BK=64) + fused dequant ----------------
// C[m][n] = sum_k xq[m][k] * w8[n][k]; 4 waves/block, each wave a 64x64 subtile
// (4x4 grid of 16x16x64 i8 MFMAs). Then y = acc * sx[m] * sw[n] + bias[n].
__global__ __launch_bounds__(256) void gemm_i8(const signed char* __restrict__ xq,
                                               const signed char* __restrict__ w8,
                                               const float* __restrict__ sx,
                                               const float* __restrict__ sw,
                                               const float* __restrict__ bias,
                                               float* __restrict__ out,
                                               int M, int N, int K) {
    __shared__ signed char As[128 * 64];  // [row][64] row-major, no pad (global_load_lds layout)
    __shared__ signed char Bs[128 * 64];

    const int tid  = threadIdx.x;
    const int lane = tid & 63;
    const int wave = tid >> 6;
    const int wm = (wave & 1) * 64;   // wave's m offset in tile
    const int wn = (wave >> 1) * 64;  // wave's n offset in tile
    const int m_block = blockIdx.y * 128;
    const int n_block = blockIdx.x * 128;

    v4i acc[4][4];
#pragma unroll
    for (int mt = 0; mt < 4; ++mt)
#pragma unroll
        for (int nt = 0; nt < 4; ++nt) {
            acc[mt][nt].x = 0; acc[mt][nt].y = 0; acc[mt][nt].z = 0; acc[mt][nt].w = 0;
        }

    // staging map: thread t covers tile byte offsets [t*16, t*16+16) per issue;
    // tile row = off>>6 (64B rows), col = off&63. LDS base is wave-uniform.
    const int sr = tid >> 2;          // 0..63 (row within half-tile)
    const int sc = (tid & 3) * 16;    // 0/16/32/48
    const signed char* aG = xq + (size_t)(m_block + sr) * K + sc;
    const signed char* bG = w8 + (size_t)(n_block + sr) * K + sc;
    signed char* aL = As + wave * 1024;
    signed char* bL = Bs + wave * 1024;

    const int fr = lane & 15;          // fragment row (m or n)
    const int fc = (lane >> 4) * 16;   // fragment k byte offset

    for (int k0 = 0; k0 < K; k0 += 64) {
        if (k0) __syncthreads();
        gll16(aG + k0, aL);
        gll16(aG + k0 + (size_t)64 * K, aL + 4096);
        gll16(bG + k0, bL);
        gll16(bG + k0 + (size_t)64 * K, bL + 4096);
        __syncthreads();  // drains vmcnt(0): LDS tiles complete & visible

        v4i af[4], bf[4];
#pragma unroll
        for (int mt = 0; mt < 4; ++mt)
            af[mt] = *(const v4i*)&As[(wm + mt * 16 + fr) * 64 + fc];
#pragma unroll
        for (int nt = 0; nt < 4; ++nt)
            bf[nt] = *(const v4i*)&Bs[(wn + nt * 16 + fr) * 64 + fc];
#pragma unroll
        for (int mt = 0; mt < 4; ++mt)
#pragma unroll
            for (int nt = 0; nt < 4; ++nt)
                acc[mt][nt] = __builtin_amdgcn_mfma_i32_16x16x64_i8(af[mt], bf[nt], acc[mt][nt], 0, 0, 0);
    }

    // epilogue: C/D layout col=lane&15, row=(lane>>4)*4+reg  (dtype-independent)
    const int lr = lane >> 4;
    const int lc = lane & 15;
#pragma unroll
    for (int mt = 0; mt < 4; ++mt) {
        const int rbase = m_block + wm + mt * 16 + lr * 4;
        float sxv[4];
#pragma unroll
        for (int r = 0; r < 4; ++r)
            sxv[r] = (rbase + r < M) ? sx[rbase + r] : 0.0f;
#pragma unroll
        for (int nt = 0; nt < 4; ++nt) {
            const int col = n_block + wn + nt * 16 + lc;
            const float swv = sw[col];
            const float bv  = bias[col];
            const int* a = (const int*)&acc[mt][nt];
#pragma unroll
            for (int r = 0; r < 4; ++r) {
                const int row = rbase + r;
                if (row < M)
                    out[(size_t)row * N + col] = (float)a[r] * sxv[r] * swv + bv;
            }
        }
    }
}

extern "C" void kernel_launch(void* const* d_in, const int* in_sizes, int n_in,
                              void* d_out, int out_size, void* d_ws, size_t ws_size,
                              hipStream_t stream) {
    const float* x       = (const float*)d_in[0];
    const int*   w_int   = (const int*)d_in[1];
    const float* scale_w = (const float*)d_in[2];
    const float* bias    = (const float*)d_in[3];
    float* out = (float*)d_out;

    const int D_OUT = in_sizes[2];             // 2560
    const int D_IN  = in_sizes[1] / D_OUT;     // 1024
    const int M     = in_sizes[0] / D_IN;      // 18464
    const int Mpad  = ((M + 127) / 128) * 128; // 18560

    // workspace layout (all 16B-aligned):
    signed char* xq = (signed char*)d_ws;                      // Mpad * D_IN  int8
    signed char* w8 = xq + (size_t)Mpad * D_IN;                // D_OUT * D_IN int8
    float*       sx = (float*)(w8 + (size_t)D_OUT * D_IN);     // Mpad floats

    quant_x<<<Mpad, 256, 0, stream>>>(x, xq, sx, M);
    const int n4 = D_OUT * D_IN / 4;
    conv_w<<<(n4 + 255) / 256, 256, 0, stream>>>(w_int, w8, n4);
    dim3 grid(D_OUT / 128, Mpad / 128);  // (20, 145): x-major sweeps N for one M-row -> A-tile L2 reuse
    gemm_i8<<<grid, dim3(256, 1, 1), 0, stream>>>(xq, w8, sx, scale_w, bias, out, M, D_OUT, D_IN);
}

// Round 2
// 317.463 us; speedup vs baseline: 1.0223x; 1.0223x over previous
//
#include <hip/hip_runtime.h>
#include <stdint.h>

typedef int v4i __attribute__((ext_vector_type(4)));

// direct global->LDS DMA, 16B per lane. LDS dest = wave-uniform base + lane*16.
__device__ __forceinline__ void gll16(const void* g, void* l) {
    __builtin_amdgcn_global_load_lds(
        (const __attribute__((address_space(1))) void*)(uintptr_t)g,
        (__attribute__((address_space(3))) void*)(uint32_t)(uintptr_t)l,
        16, 0, 0);
}

// ---------------- Kernel 1: per-row dynamic int8 quantization of x ----------------
__global__ __launch_bounds__(256) void quant_x(const float* __restrict__ x,
                                               signed char* __restrict__ xq,
                                               float* __restrict__ sx, int M) {
    const int row = blockIdx.x;
    const int tid = threadIdx.x;
    signed char* qrow = xq + (size_t)row * 1024;
    if (row >= M) {  // zero the pad rows (uniform branch per block)
        ((char4*)qrow)[tid] = make_char4(0, 0, 0, 0);
        if (tid == 0) sx[row] = 0.0f;
        return;
    }
    const float4 v = ((const float4*)(x + (size_t)row * 1024))[tid];
    float a = fmaxf(fmaxf(fabsf(v.x), fabsf(v.y)), fmaxf(fabsf(v.z), fabsf(v.w)));
#pragma unroll
    for (int off = 32; off > 0; off >>= 1)
        a = fmaxf(a, __shfl_xor(a, off));
    __shared__ float red[4];
    if ((tid & 63) == 0) red[tid >> 6] = a;
    __syncthreads();
    const float am = fmaxf(fmaxf(red[0], red[1]), fmaxf(red[2], red[3]));
    const float amc = fmaxf(am, 1e-8f);
    const float scale = amc * (1.0f / 127.0f);
    const float inv = 127.0f / amc;
    char4 q;
    q.x = (signed char)(int)rintf(v.x * inv);
    q.y = (signed char)(int)rintf(v.y * inv);
    q.z = (signed char)(int)rintf(v.z * inv);
    q.w = (signed char)(int)rintf(v.w * inv);
    ((char4*)qrow)[tid] = q;
    if (tid == 0) sx[row] = scale;
}

// ---------------- Kernel 2: w_int (int32, values in [-127,127]) -> int8 ----------------
__global__ __launch_bounds__(256) void conv_w(const int* __restrict__ w,
                                              signed char* __restrict__ w8, int n4) {
    const int i = blockIdx.x * 256 + threadIdx.x;
    if (i < n4) {
        const int4 v = ((const int4*)w)[i];
        char4 c;
        c.x = (signed char)v.x; c.y = (signed char)v.y;
        c.z = (signed char)v.z; c.w = (signed char)v.w;
        ((char4*)w8)[i] = c;
    }
}

// ---------------- Kernel 3: int8 GEMM (128x128 tile, BK=64) + fused dequant ----------------
// C[m][n] = sum_k xq[m][k] * w8[n][k]; 4 waves/block, each wave a 64x64 subtile
// (4x4 grid of 16x16x64 i8 MFMAs). Then y = acc * sx[m] * sw[n] + bias[n].
//
// LDS layout is XOR-swizzled: tile row r stores its four 16B K-chunks permuted by
// key=(r>>1)&3 (chunk c holds global chunk c^key). Since global_load_lds cannot
// scatter per-lane, the swizzle is applied on the GLOBAL fetch address; fragment
// reads un-swizzle with the same key. This turns the 8-way bank conflict of the
// 64B-row-stride b128 reads into free 2-way (2 lanes per 4-bank group).
__global__ __launch_bounds__(256) void gemm_i8(const signed char* __restrict__ xq,
                                               const signed char* __restrict__ w8,
                                               const float* __restrict__ sx,
                                               const float* __restrict__ sw,
                                               const float* __restrict__ bias,
                                               float* __restrict__ out,
                                               int M, int N, int K) {
    __shared__ signed char As[128 * 64];
    __shared__ signed char Bs[128 * 64];

    const int tid  = threadIdx.x;
    const int lane = tid & 63;
    const int wave = tid >> 6;
    const int wm = (wave & 1) * 64;   // wave's m offset in tile
    const int wn = (wave >> 1) * 64;  // wave's n offset in tile
    const int m_block = blockIdx.y * 128;
    const int n_block = blockIdx.x * 128;

    v4i acc[4][4];
#pragma unroll
    for (int mt = 0; mt < 4; ++mt)
#pragma unroll
        for (int nt = 0; nt < 4; ++nt) {
            acc[mt][nt].x = 0; acc[mt][nt].y = 0; acc[mt][nt].z = 0; acc[mt][nt].w = 0;
        }

    // staging map: thread t owns LDS slot (row sr, chunk tid&3); it fetches the
    // swizzled global chunk (tid&3)^((sr>>1)&3). Valid for both halves (sr, sr+64)
    // since the key is invariant under +64.
    const int sr = tid >> 2;                                  // 0..63
    const int sc = ((tid & 3) ^ ((sr >> 1) & 3)) * 16;        // swizzled global chunk
    const signed char* aG = xq + (size_t)(m_block + sr) * K + sc;
    const signed char* bG = w8 + (size_t)(n_block + sr) * K + sc;
    signed char* aL = As + wave * 1024;
    signed char* bL = Bs + wave * 1024;

    const int fr  = lane & 15;                                 // fragment row (m or n)
    const int fcs = (((lane >> 4) ^ ((lane >> 1) & 3))) * 16;  // swizzled K-chunk offset

    for (int k0 = 0; k0 < K; k0 += 64) {
        if (k0) __syncthreads();
        gll16(aG + k0, aL);
        gll16(aG + k0 + (size_t)64 * K, aL + 4096);
        gll16(bG + k0, bL);
        gll16(bG + k0 + (size_t)64 * K, bL + 4096);
        __syncthreads();  // drains vmcnt(0): LDS tiles complete & visible

        v4i af[4], bf[4];
#pragma unroll
        for (int mt = 0; mt < 4; ++mt)
            af[mt] = *(const v4i*)&As[(wm + mt * 16 + fr) * 64 + fcs];
#pragma unroll
        for (int nt = 0; nt < 4; ++nt)
            bf[nt] = *(const v4i*)&Bs[(wn + nt * 16 + fr) * 64 + fcs];
#pragma unroll
        for (int mt = 0; mt < 4; ++mt)
#pragma unroll
            for (int nt = 0; nt < 4; ++nt)
                acc[mt][nt] = __builtin_amdgcn_mfma_i32_16x16x64_i8(af[mt], bf[nt], acc[mt][nt], 0, 0, 0);
    }

    // epilogue: C/D layout col=lane&15, row=(lane>>4)*4+reg  (dtype-independent)
    const int lr = lane >> 4;
    const int lc = lane & 15;
#pragma unroll
    for (int mt = 0; mt < 4; ++mt) {
        const int rbase = m_block + wm + mt * 16 + lr * 4;
        float sxv[4];
#pragma unroll
        for (int r = 0; r < 4; ++r)
            sxv[r] = (rbase + r < M) ? sx[rbase + r] : 0.0f;
#pragma unroll
        for (int nt = 0; nt < 4; ++nt) {
            const int col = n_block + wn + nt * 16 + lc;
            const float swv = sw[col];
            const float bv  = bias[col];
            const int* a = (const int*)&acc[mt][nt];
#pragma unroll
            for (int r = 0; r < 4; ++r) {
                const int row = rbase + r;
                if (row < M)
                    out[(size_t)row * N + col] = (float)a[r] * sxv[r] * swv + bv;
            }
        }
    }
}

extern "C" void kernel_launch(void* const* d_in, const int* in_sizes, int n_in,
                              void* d_out, int out_size, void* d_ws, size_t ws_size,
                              hipStream_t stream) {
    const float* x       = (const float*)d_in[0];
    const int*   w_int   = (const int*)d_in[1];
    const float* scale_w = (const float*)d_in[2];
    const float* bias    = (const float*)d_in[3];
    float* out = (float*)d_out;

    const int D_OUT = in_sizes[2];             // 2560
    const int D_IN  = in_sizes[1] / D_OUT;     // 1024
    const int M     = in_sizes[0] / D_IN;      // 18464
    const int Mpad  = ((M + 127) / 128) * 128; // 18560

    // workspace layout (all 16B-aligned):
    signed char* xq = (signed char*)d_ws;                      // Mpad * D_IN  int8
    signed char* w8 = xq + (size_t)Mpad * D_IN;                // D_OUT * D_IN int8
    float*       sx = (float*)(w8 + (size_t)D_OUT * D_IN);     // Mpad floats

    quant_x<<<Mpad, 256, 0, stream>>>(x, xq, sx, M);
    const int n4 = D_OUT * D_IN / 4;
    conv_w<<<(n4 + 255) / 256, 256, 0, stream>>>(w_int, w8, n4);
    dim3 grid(D_OUT / 128, Mpad / 128);  // (20, 145): x-major sweeps N for one M-row -> A-tile L2 reuse
    gemm_i8<<<grid, dim3(256, 1, 1), 0, stream>>>(xq, w8, sx, scale_w, bias, out, M, D_OUT, D_IN);
}